// Round 2
// baseline (5394.764 us; speedup 1.0000x reference)
//
#include <hip/hip_runtime.h>

#define SCALEF  0.37796447300922720f   // 1/sqrt(7)
#define EPSF    1e-10f
#define MAXENT  6.93147180559945286f   // ln(1024)

// ---------------- helpers ----------------
__device__ __forceinline__ float wave_sum(float v) {
#pragma unroll
  for (int off = 32; off > 0; off >>= 1) v += __shfl_xor(v, off);
  return v;
}
__device__ __forceinline__ float wave_max(float v) {
#pragma unroll
  for (int off = 32; off > 0; off >>= 1) v = fmaxf(v, __shfl_xor(v, off));
  return v;
}
__device__ __forceinline__ void fma4(float a, float4 b, float4& c) {
  c.x = fmaf(a, b.x, c.x); c.y = fmaf(a, b.y, c.y);
  c.z = fmaf(a, b.z, c.z); c.w = fmaf(a, b.w, c.w);
}
// P0_ij = (0.5*(exp(s1*scale - a1) + exp(s2*scale - a2)) + EPS)^10
__device__ __forceinline__ float p0val(float s1, float s2, float a1, float a2) {
  float p = 0.5f * (__expf(fmaf(s1, SCALEF, -a1)) + __expf(fmaf(s2, SCALEF, -a2))) + EPSF;
  float p2 = p * p, p4 = p2 * p2, p5 = p4 * p;
  return p5 * p5;
}

// ---------------- kernel 0: QKV projection (d-major layouts) + R/C init ----------------
__global__ __launch_bounds__(256) void qkv_kernel(
    const float* __restrict__ x,
    const float* __restrict__ Wq, const float* __restrict__ bq,
    const float* __restrict__ Wk, const float* __restrict__ bk,
    const float* __restrict__ Wv, const float* __restrict__ bv,
    float* __restrict__ Qt, float* __restrict__ Kt, float* __restrict__ Vt,
    float* __restrict__ R, float* __restrict__ C) {
  int row = blockIdx.x * 256 + threadIdx.x;     // 65536 rows
  int b = row >> 10, i = row & 1023;
  float xv[14];
#pragma unroll
  for (int k = 0; k < 14; k++) xv[k] = x[row * 14 + k];
#pragma unroll
  for (int d = 0; d < 14; d++) {
    float q = bq[d], kk = bk[d], vv = bv[d];
#pragma unroll
    for (int k = 0; k < 14; k++) {
      q  = fmaf(xv[k], Wq[d * 14 + k], q);
      kk = fmaf(xv[k], Wk[d * 14 + k], kk);
      vv = fmaf(xv[k], Wv[d * 14 + k], vv);
    }
    int o = b * 14336 + d * 1024 + i;
    Qt[o] = q; Kt[o] = kk; Vt[o] = vv;
  }
  R[row] = 1.0f;
  C[row] = 1.0f;
}

// ---------------- kernel 1: fused attention + entropy/certainty + softmax stats ----------------
// 1024 threads = 16 waves, one query row per wave; K then V staged in 56KB LDS (two phases)
__global__ __launch_bounds__(1024) void attn_kernel(
    const float* __restrict__ Qt, const float* __restrict__ Kt, const float* __restrict__ Vt,
    const float* __restrict__ cert_in,
    float* __restrict__ A1, float* __restrict__ A2,
    float* __restrict__ attn_o, float* __restrict__ cert_out) {
  __shared__ float4 Sl[3584];                   // 56 KB, holds K then V
  int b = blockIdx.x >> 6;                      // 64 blocks per batch
  int rg = blockIdx.x & 63;                     // 16 rows per block
  int tid = threadIdx.x;
  const float4* Ktb = (const float4*)(Kt + b * 14336);
  const float4* Vtb = (const float4*)(Vt + b * 14336);
  for (int idx = tid; idx < 3584; idx += 1024) Sl[idx] = Ktb[idx];
  __syncthreads();

  int wave = tid >> 6, lane = tid & 63;
  int i = rg * 16 + wave;
  int row = b * 1024 + i;
  float q[14];
#pragma unroll
  for (int d = 0; d < 14; d++) q[d] = Qt[b * 14336 + d * 1024 + i];

  float4 e1[4], e2[4];
  float m1 = -1e30f, m2 = -1e30f;
#pragma unroll
  for (int t = 0; t < 4; t++) {
    int g = t * 64 + lane;
    float4 s1 = {0, 0, 0, 0}, s2 = {0, 0, 0, 0};
#pragma unroll
    for (int d = 0; d < 7; d++)  fma4(q[d], Sl[d * 256 + g], s1);
#pragma unroll
    for (int d = 7; d < 14; d++) fma4(q[d], Sl[d * 256 + g], s2);
    s1.x *= SCALEF; s1.y *= SCALEF; s1.z *= SCALEF; s1.w *= SCALEF;
    s2.x *= SCALEF; s2.y *= SCALEF; s2.z *= SCALEF; s2.w *= SCALEF;
    e1[t] = s1; e2[t] = s2;
    m1 = fmaxf(m1, fmaxf(fmaxf(s1.x, s1.y), fmaxf(s1.z, s1.w)));
    m2 = fmaxf(m2, fmaxf(fmaxf(s2.x, s2.y), fmaxf(s2.z, s2.w)));
  }
  m1 = wave_max(m1); m2 = wave_max(m2);
  float l1 = 0.f, l2 = 0.f;
#pragma unroll
  for (int t = 0; t < 4; t++) {
    e1[t].x = __expf(e1[t].x - m1); e1[t].y = __expf(e1[t].y - m1);
    e1[t].z = __expf(e1[t].z - m1); e1[t].w = __expf(e1[t].w - m1);
    e2[t].x = __expf(e2[t].x - m2); e2[t].y = __expf(e2[t].y - m2);
    e2[t].z = __expf(e2[t].z - m2); e2[t].w = __expf(e2[t].w - m2);
    l1 += e1[t].x + e1[t].y + e1[t].z + e1[t].w;
    l2 += e2[t].x + e2[t].y + e2[t].z + e2[t].w;
  }
  l1 = wave_sum(l1); l2 = wave_sum(l2);
  float inv1 = 1.0f / l1, inv2 = 1.0f / l2;

  // phase 2: swap V into LDS
  __syncthreads();
  for (int idx = tid; idx < 3584; idx += 1024) Sl[idx] = Vtb[idx];
  __syncthreads();

  float acc[14];
#pragma unroll
  for (int d = 0; d < 14; d++) acc[d] = 0.f;
  float ent = 0.f;
#pragma unroll
  for (int t = 0; t < 4; t++) {
    int g = t * 64 + lane;
    float4 p1 = e1[t], p2 = e2[t];
#pragma unroll
    for (int d = 0; d < 7; d++) {
      float4 vv = Sl[d * 256 + g];
      acc[d] += p1.x * vv.x + p1.y * vv.y + p1.z * vv.z + p1.w * vv.w;
    }
#pragma unroll
    for (int d = 7; d < 14; d++) {
      float4 vv = Sl[d * 256 + g];
      acc[d] += p2.x * vv.x + p2.y * vv.y + p2.z * vv.z + p2.w * vv.w;
    }
    float a;
    a = 0.5f * (p1.x * inv1 + p2.x * inv2); ent -= a * __logf(a + EPSF);
    a = 0.5f * (p1.y * inv1 + p2.y * inv2); ent -= a * __logf(a + EPSF);
    a = 0.5f * (p1.z * inv1 + p2.z * inv2); ent -= a * __logf(a + EPSF);
    a = 0.5f * (p1.w * inv1 + p2.w * inv2); ent -= a * __logf(a + EPSF);
  }
  ent = wave_sum(ent);
#pragma unroll
  for (int d = 0; d < 14; d++) acc[d] = wave_sum(acc[d]);

  if (lane == 0) {
    A1[row] = m1 + __logf(l1);
    A2[row] = m2 + __logf(l2);
#pragma unroll
    for (int d = 0; d < 14; d++)
      attn_o[row * 14 + d] = acc[d] * (d < 7 ? inv1 : inv2);
    float sg = 1.0f / (1.0f + __expf(ent - MAXENT));   // sigmoid(MAXENT - ent)
    cert_out[row] = fmaxf(cert_in[row], sg);
  }
}

// ---------------- kernel 2: output projection ----------------
__global__ __launch_bounds__(256) void proj_kernel(
    const float* __restrict__ attn_o, const float* __restrict__ Wo,
    const float* __restrict__ bo, float* __restrict__ out) {
  int idx = blockIdx.x * 256 + threadIdx.x;     // 917504 = 65536*14
  if (idx >= 917504) return;
  int row = idx / 14, d = idx - row * 14;
  float s = bo[d];
  const float* ar = attn_o + row * 14;
  const float* wr = Wo + d * 14;
#pragma unroll
  for (int k = 0; k < 14; k++) s = fmaf(ar[k], wr[k], s);
  out[idx] = s;
}

// ---------------- Sinkhorn pass A: u = P0 @ C, update R ----------------
// 512 blocks; each stages K once (56KB) then processes 4 groups of 32 rows (128 rows)
__global__ __launch_bounds__(512) void sinkA_kernel(
    const float* __restrict__ Qt, const float* __restrict__ Kt,
    const float* __restrict__ A1, const float* __restrict__ A2,
    const float* __restrict__ C, float* __restrict__ R) {
  __shared__ float4 Kl[3584];
  int b = blockIdx.x >> 3, blk = blockIdx.x & 7;
  int tid = threadIdx.x;
  const float4* Ktb = (const float4*)(Kt + b * 14336);
  for (int idx = tid; idx < 3584; idx += 512) Kl[idx] = Ktb[idx];
  __syncthreads();

  int wave = tid >> 6, lane = tid & 63;
  const float4* Cb = (const float4*)(C + b * 1024);

  for (int grp = 0; grp < 4; grp++) {
    int i0 = blk * 128 + grp * 32 + wave * 4;
    float q[4][14], a1[4], a2[4], u[4];
#pragma unroll
    for (int rr = 0; rr < 4; rr++) {
#pragma unroll
      for (int d = 0; d < 14; d++) q[rr][d] = Qt[b * 14336 + d * 1024 + i0 + rr];
      a1[rr] = A1[b * 1024 + i0 + rr];
      a2[rr] = A2[b * 1024 + i0 + rr];
      u[rr] = 0.f;
    }
#pragma unroll
    for (int t = 0; t < 4; t++) {
      int g = t * 64 + lane;
      float4 kv[14];
#pragma unroll
      for (int d = 0; d < 14; d++) kv[d] = Kl[d * 256 + g];
      float4 cv = Cb[g];
#pragma unroll
      for (int rr = 0; rr < 4; rr++) {
        float4 s1 = {0, 0, 0, 0}, s2 = {0, 0, 0, 0};
#pragma unroll
        for (int d = 0; d < 7; d++)  fma4(q[rr][d], kv[d], s1);
#pragma unroll
        for (int d = 7; d < 14; d++) fma4(q[rr][d], kv[d], s2);
        u[rr] += p0val(s1.x, s2.x, a1[rr], a2[rr]) * cv.x;
        u[rr] += p0val(s1.y, s2.y, a1[rr], a2[rr]) * cv.y;
        u[rr] += p0val(s1.z, s2.z, a1[rr], a2[rr]) * cv.z;
        u[rr] += p0val(s1.w, s2.w, a1[rr], a2[rr]) * cv.w;
      }
    }
#pragma unroll
    for (int rr = 0; rr < 4; rr++) u[rr] = wave_sum(u[rr]);
    if (lane == 0) {
#pragma unroll
      for (int rr = 0; rr < 4; rr++) {
        int o = b * 1024 + i0 + rr;
        float rv = R[o];
        rv = rv / fmaf(rv, u[rr], EPSF);
        R[o] = fminf(rv, 1e37f);
      }
    }
  }
}

// ---------------- Sinkhorn pass B: v = P0^T @ R, update C ----------------
__global__ __launch_bounds__(512) void sinkB_kernel(
    const float* __restrict__ Qt, const float* __restrict__ Kt,
    const float* __restrict__ A1, const float* __restrict__ A2,
    const float* __restrict__ R, float* __restrict__ C) {
  __shared__ float4 Ql[3584];
  int b = blockIdx.x >> 3, blk = blockIdx.x & 7;
  int tid = threadIdx.x;
  const float4* Qtb = (const float4*)(Qt + b * 14336);
  for (int idx = tid; idx < 3584; idx += 512) Ql[idx] = Qtb[idx];
  __syncthreads();

  int wave = tid >> 6, lane = tid & 63;
  const float4* A1b = (const float4*)(A1 + b * 1024);
  const float4* A2b = (const float4*)(A2 + b * 1024);
  const float4* Rb  = (const float4*)(R + b * 1024);

  for (int grp = 0; grp < 4; grp++) {
    int j0 = blk * 128 + grp * 32 + wave * 4;
    float kk[4][14], v[4];
#pragma unroll
    for (int rr = 0; rr < 4; rr++) {
#pragma unroll
      for (int d = 0; d < 14; d++) kk[rr][d] = Kt[b * 14336 + d * 1024 + j0 + rr];
      v[rr] = 0.f;
    }
#pragma unroll
    for (int t = 0; t < 4; t++) {
      int g = t * 64 + lane;
      float4 qv[14];
#pragma unroll
      for (int d = 0; d < 14; d++) qv[d] = Ql[d * 256 + g];
      float4 a1v = A1b[g], a2v = A2b[g], rv = Rb[g];
#pragma unroll
      for (int rr = 0; rr < 4; rr++) {
        float4 s1 = {0, 0, 0, 0}, s2 = {0, 0, 0, 0};
#pragma unroll
        for (int d = 0; d < 7; d++)  fma4(kk[rr][d], qv[d], s1);
#pragma unroll
        for (int d = 7; d < 14; d++) fma4(kk[rr][d], qv[d], s2);
        v[rr] += p0val(s1.x, s2.x, a1v.x, a2v.x) * rv.x;
        v[rr] += p0val(s1.y, s2.y, a1v.y, a2v.y) * rv.y;
        v[rr] += p0val(s1.z, s2.z, a1v.z, a2v.z) * rv.z;
        v[rr] += p0val(s1.w, s2.w, a1v.w, a2v.w) * rv.w;
      }
    }
#pragma unroll
    for (int rr = 0; rr < 4; rr++) v[rr] = wave_sum(v[rr]);
    if (lane == 0) {
#pragma unroll
      for (int rr = 0; rr < 4; rr++) {
        int o = b * 1024 + j0 + rr;
        float cv = C[o];
        cv = cv / fmaf(cv, v[rr], EPSF);
        C[o] = fminf(cv, 1e37f);
      }
    }
  }
}

// ---------------- final argmax over P0_ij * C_j + permutation gather ----------------
// 512 blocks; stage K once, 16 groups of 8 rows (one row per wave)
__global__ __launch_bounds__(512) void argmax_kernel(
    const float* __restrict__ Qt, const float* __restrict__ Kt,
    const float* __restrict__ A1, const float* __restrict__ A2,
    const float* __restrict__ C, const int* __restrict__ perm,
    float* __restrict__ perm_out) {
  __shared__ float4 Kl[3584];
  int b = blockIdx.x >> 3, blk = blockIdx.x & 7;
  int tid = threadIdx.x;
  const float4* Ktb = (const float4*)(Kt + b * 14336);
  for (int idx = tid; idx < 3584; idx += 512) Kl[idx] = Ktb[idx];
  __syncthreads();

  int wave = tid >> 6, lane = tid & 63;
  const float4* Cb = (const float4*)(C + b * 1024);

  for (int grp = 0; grp < 16; grp++) {
    int i = blk * 128 + grp * 8 + wave;
    int row = b * 1024 + i;
    float q[14];
#pragma unroll
    for (int d = 0; d < 14; d++) q[d] = Qt[b * 14336 + d * 1024 + i];
    float a1 = A1[row], a2 = A2[row];

    float best = -1.0f;
    int bj = 0;
#pragma unroll
    for (int t = 0; t < 4; t++) {
      int g = t * 64 + lane;
      float4 kv[14];
#pragma unroll
      for (int d = 0; d < 14; d++) kv[d] = Kl[d * 256 + g];
      float4 cv = Cb[g];
      float4 s1 = {0, 0, 0, 0}, s2 = {0, 0, 0, 0};
#pragma unroll
      for (int d = 0; d < 7; d++)  fma4(q[d], kv[d], s1);
#pragma unroll
      for (int d = 7; d < 14; d++) fma4(q[d], kv[d], s2);
      float val;
      val = p0val(s1.x, s2.x, a1, a2) * cv.x; if (val > best) { best = val; bj = 4 * g + 0; }
      val = p0val(s1.y, s2.y, a1, a2) * cv.y; if (val > best) { best = val; bj = 4 * g + 1; }
      val = p0val(s1.z, s2.z, a1, a2) * cv.z; if (val > best) { best = val; bj = 4 * g + 2; }
      val = p0val(s1.w, s2.w, a1, a2) * cv.w; if (val > best) { best = val; bj = 4 * g + 3; }
    }
    // cross-lane argmax, first-index tie-break
#pragma unroll
    for (int off = 32; off > 0; off >>= 1) {
      float ob = __shfl_xor(best, off);
      int oj = __shfl_xor(bj, off);
      if (ob > best || (ob == best && oj < bj)) { best = ob; bj = oj; }
    }
    if (lane == 0) perm_out[row] = (float)perm[b * 1024 + bj];
  }
}

// ---------------- launch ----------------
extern "C" void kernel_launch(void* const* d_in, const int* in_sizes, int n_in,
                              void* d_out, int out_size, void* d_ws, size_t ws_size,
                              hipStream_t stream) {
  const float* x    = (const float*)d_in[0];
  const float* cert = (const float*)d_in[1];
  const int*   perm = (const int*)d_in[2];
  const float* Wq = (const float*)d_in[3];
  const float* bq = (const float*)d_in[4];
  const float* Wk = (const float*)d_in[5];
  const float* bk = (const float*)d_in[6];
  const float* Wv = (const float*)d_in[7];
  const float* bv = (const float*)d_in[8];
  const float* Wo = (const float*)d_in[9];
  const float* bo = (const float*)d_in[10];

  float* out      = (float*)d_out;            // 917504
  float* cert_out = out + 917504;             // 65536
  float* perm_out = out + 983040;             // 65536

  float* ws = (float*)d_ws;
  float* Qt = ws;                    // 917504
  float* Kt = Qt + 917504;           // 917504
  float* Vt = Kt + 917504;           // 917504
  float* A1 = Vt + 917504;           // 65536
  float* A2 = A1 + 65536;            // 65536
  float* R  = A2 + 65536;            // 65536
  float* C  = R + 65536;             // 65536
  float* attn_o = C + 65536;         // 917504  (total ~15.7 MB)

  qkv_kernel<<<256, 256, 0, stream>>>(x, Wq, bq, Wk, bk, Wv, bv, Qt, Kt, Vt, R, C);
  attn_kernel<<<4096, 1024, 0, stream>>>(Qt, Kt, Vt, cert, A1, A2, attn_o, cert_out);
  proj_kernel<<<3584, 256, 0, stream>>>(attn_o, Wo, bo, out);
  for (int it = 0; it < 20; it++) {
    sinkA_kernel<<<512, 512, 0, stream>>>(Qt, Kt, A1, A2, C, R);
    sinkB_kernel<<<512, 512, 0, stream>>>(Qt, Kt, A1, A2, R, C);
  }
  argmax_kernel<<<512, 512, 0, stream>>>(Qt, Kt, A1, A2, C, perm, perm_out);
}

// Round 3
// 2950.110 us; speedup vs baseline: 1.8287x; 1.8287x over previous
//
#include <hip/hip_runtime.h>

#define SCALEF  0.37796447300922720f   // 1/sqrt(7)
#define EPSF    1e-10f
#define MAXENT  6.93147180559945286f   // ln(1024)

// ---------------- helpers ----------------
__device__ __forceinline__ float wave_sum(float v) {
#pragma unroll
  for (int off = 32; off > 0; off >>= 1) v += __shfl_xor(v, off);
  return v;
}
__device__ __forceinline__ float wave_max(float v) {
#pragma unroll
  for (int off = 32; off > 0; off >>= 1) v = fmaxf(v, __shfl_xor(v, off));
  return v;
}
__device__ __forceinline__ void fma4(float a, float4 b, float4& c) {
  c.x = fmaf(a, b.x, c.x); c.y = fmaf(a, b.y, c.y);
  c.z = fmaf(a, b.z, c.z); c.w = fmaf(a, b.w, c.w);
}
// P0 = (E1*exp(s1) + E2*exp(s2) + EPS)^10, with E_h = 0.5*exp(-a_h) prefolded
__device__ __forceinline__ float p0e(float s1, float s2, float E1, float E2) {
  float p = fmaf(E1, __expf(s1), fmaf(E2, __expf(s2), EPSF));
  float p2 = p * p, p4 = p2 * p2, p5 = p4 * p;
  return p5 * p5;
}

// ---------------- kernel 0: QKV projection (d-major, Q pre-scaled) + R/C init ----------------
__global__ __launch_bounds__(256) void qkv_kernel(
    const float* __restrict__ x,
    const float* __restrict__ Wq, const float* __restrict__ bq,
    const float* __restrict__ Wk, const float* __restrict__ bk,
    const float* __restrict__ Wv, const float* __restrict__ bv,
    float* __restrict__ Qt, float* __restrict__ Kt, float* __restrict__ Vt,
    float* __restrict__ R, float* __restrict__ C) {
  int row = blockIdx.x * 256 + threadIdx.x;     // 65536 rows
  int b = row >> 10, i = row & 1023;
  float xv[14];
#pragma unroll
  for (int k = 0; k < 14; k++) xv[k] = x[row * 14 + k];
#pragma unroll
  for (int d = 0; d < 14; d++) {
    float q = bq[d], kk = bk[d], vv = bv[d];
#pragma unroll
    for (int k = 0; k < 14; k++) {
      q  = fmaf(xv[k], Wq[d * 14 + k], q);
      kk = fmaf(xv[k], Wk[d * 14 + k], kk);
      vv = fmaf(xv[k], Wv[d * 14 + k], vv);
    }
    int o = b * 14336 + d * 1024 + i;
    Qt[o] = q * SCALEF;   // pre-scaled: scores = dot(Qt,K) directly
    Kt[o] = kk; Vt[o] = vv;
  }
  R[row] = 1.0f;
  C[row] = 1.0f;
}

// ---------------- kernel 1: fused attention + entropy/certainty + E1/E2 stats ----------------
// 1024 threads = 16 waves, one query row per wave; K then V staged in 56KB LDS (two phases)
// launch_bounds(1024,4): <=128 VGPR so e1/e2 stay in registers (round-2 spilled at 64)
__global__ __launch_bounds__(1024, 4) void attn_kernel(
    const float* __restrict__ Qt, const float* __restrict__ Kt, const float* __restrict__ Vt,
    const float* __restrict__ cert_in,
    float* __restrict__ E1o, float* __restrict__ E2o,
    float* __restrict__ attn_o, float* __restrict__ cert_out) {
  __shared__ float4 Sl[3584];                   // 56 KB, holds K then V
  int b = blockIdx.x >> 6;                      // 64 blocks per batch
  int rg = blockIdx.x & 63;                     // 16 rows per block
  int tid = threadIdx.x;
  const float4* Ktb = (const float4*)(Kt + b * 14336);
  const float4* Vtb = (const float4*)(Vt + b * 14336);
  for (int idx = tid; idx < 3584; idx += 1024) Sl[idx] = Ktb[idx];
  __syncthreads();

  int wave = tid >> 6, lane = tid & 63;
  int i = rg * 16 + wave;
  int row = b * 1024 + i;
  float q[14];
#pragma unroll
  for (int d = 0; d < 14; d++) q[d] = Qt[b * 14336 + d * 1024 + i];

  float4 e1[4], e2[4];
  float m1 = -1e30f, m2 = -1e30f;
#pragma unroll
  for (int t = 0; t < 4; t++) {
    int g = t * 64 + lane;
    float4 s1 = {0, 0, 0, 0}, s2 = {0, 0, 0, 0};
#pragma unroll
    for (int d = 0; d < 7; d++)  fma4(q[d], Sl[d * 256 + g], s1);
#pragma unroll
    for (int d = 7; d < 14; d++) fma4(q[d], Sl[d * 256 + g], s2);
    e1[t] = s1; e2[t] = s2;
    m1 = fmaxf(m1, fmaxf(fmaxf(s1.x, s1.y), fmaxf(s1.z, s1.w)));
    m2 = fmaxf(m2, fmaxf(fmaxf(s2.x, s2.y), fmaxf(s2.z, s2.w)));
  }
  m1 = wave_max(m1); m2 = wave_max(m2);
  float l1 = 0.f, l2 = 0.f;
#pragma unroll
  for (int t = 0; t < 4; t++) {
    e1[t].x = __expf(e1[t].x - m1); e1[t].y = __expf(e1[t].y - m1);
    e1[t].z = __expf(e1[t].z - m1); e1[t].w = __expf(e1[t].w - m1);
    e2[t].x = __expf(e2[t].x - m2); e2[t].y = __expf(e2[t].y - m2);
    e2[t].z = __expf(e2[t].z - m2); e2[t].w = __expf(e2[t].w - m2);
    l1 += e1[t].x + e1[t].y + e1[t].z + e1[t].w;
    l2 += e2[t].x + e2[t].y + e2[t].z + e2[t].w;
  }
  l1 = wave_sum(l1); l2 = wave_sum(l2);
  float inv1 = 1.0f / l1, inv2 = 1.0f / l2;

  // phase 2: swap V into LDS
  __syncthreads();
  for (int idx = tid; idx < 3584; idx += 1024) Sl[idx] = Vtb[idx];
  __syncthreads();

  float acc[14];
#pragma unroll
  for (int d = 0; d < 14; d++) acc[d] = 0.f;
  float ent = 0.f;
#pragma unroll
  for (int t = 0; t < 4; t++) {
    int g = t * 64 + lane;
    float4 p1 = e1[t], p2 = e2[t];
#pragma unroll
    for (int d = 0; d < 7; d++) {
      float4 vv = Sl[d * 256 + g];
      acc[d] += p1.x * vv.x + p1.y * vv.y + p1.z * vv.z + p1.w * vv.w;
    }
#pragma unroll
    for (int d = 7; d < 14; d++) {
      float4 vv = Sl[d * 256 + g];
      acc[d] += p2.x * vv.x + p2.y * vv.y + p2.z * vv.z + p2.w * vv.w;
    }
    float a;
    a = 0.5f * (p1.x * inv1 + p2.x * inv2); ent -= a * __logf(a + EPSF);
    a = 0.5f * (p1.y * inv1 + p2.y * inv2); ent -= a * __logf(a + EPSF);
    a = 0.5f * (p1.z * inv1 + p2.z * inv2); ent -= a * __logf(a + EPSF);
    a = 0.5f * (p1.w * inv1 + p2.w * inv2); ent -= a * __logf(a + EPSF);
  }
  ent = wave_sum(ent);
#pragma unroll
  for (int d = 0; d < 14; d++) acc[d] = wave_sum(acc[d]);

  if (lane == 0) {
    // E_h = 0.5*exp(-(m_h + log l_h)) = 0.5*exp(-m_h)/l_h
    E1o[row] = 0.5f * __expf(-m1) * inv1;
    E2o[row] = 0.5f * __expf(-m2) * inv2;
#pragma unroll
    for (int d = 0; d < 14; d++)
      attn_o[row * 14 + d] = acc[d] * (d < 7 ? inv1 : inv2);
    float sg = 1.0f / (1.0f + __expf(ent - MAXENT));   // sigmoid(MAXENT - ent)
    cert_out[row] = fmaxf(cert_in[row], sg);
  }
}

// ---------------- kernel 2: output projection ----------------
__global__ __launch_bounds__(256) void proj_kernel(
    const float* __restrict__ attn_o, const float* __restrict__ Wo,
    const float* __restrict__ bo, float* __restrict__ out) {
  int idx = blockIdx.x * 256 + threadIdx.x;     // 917504 = 65536*14
  if (idx >= 917504) return;
  int row = idx / 14, d = idx - row * 14;
  float s = bo[d];
  const float* ar = attn_o + row * 14;
  const float* wr = Wo + d * 14;
#pragma unroll
  for (int k = 0; k < 14; k++) s = fmaf(ar[k], wr[k], s);
  out[idx] = s;
}

// ---------------- Sinkhorn pass A: u = P0 @ C, update R ----------------
// round-1 proven shape: 2048 blocks x 512 thr, 8 waves x 4 rows = 32 rows/block
__global__ __launch_bounds__(512) void sinkA_kernel(
    const float* __restrict__ Qt, const float* __restrict__ Kt,
    const float* __restrict__ E1, const float* __restrict__ E2,
    const float* __restrict__ C, float* __restrict__ R) {
  __shared__ float4 Kl[3584];
  int b = blockIdx.x >> 5, blk = blockIdx.x & 31;
  int tid = threadIdx.x;
  const float4* Ktb = (const float4*)(Kt + b * 14336);
  for (int idx = tid; idx < 3584; idx += 512) Kl[idx] = Ktb[idx];
  __syncthreads();

  int wave = tid >> 6, lane = tid & 63;
  int i0 = blk * 32 + wave * 4;
  float q[4][14], e1r[4], e2r[4], u[4];
#pragma unroll
  for (int rr = 0; rr < 4; rr++) {
#pragma unroll
    for (int d = 0; d < 14; d++) q[rr][d] = Qt[b * 14336 + d * 1024 + i0 + rr];
    e1r[rr] = E1[b * 1024 + i0 + rr];
    e2r[rr] = E2[b * 1024 + i0 + rr];
    u[rr] = 0.f;
  }
  const float4* Cb = (const float4*)(C + b * 1024);
#pragma unroll
  for (int t = 0; t < 4; t++) {
    int g = t * 64 + lane;
    float4 kv[14];
#pragma unroll
    for (int d = 0; d < 14; d++) kv[d] = Kl[d * 256 + g];
    float4 cv = Cb[g];
#pragma unroll
    for (int rr = 0; rr < 4; rr++) {
      float4 s1 = {0, 0, 0, 0}, s2 = {0, 0, 0, 0};
#pragma unroll
      for (int d = 0; d < 7; d++)  fma4(q[rr][d], kv[d], s1);
#pragma unroll
      for (int d = 7; d < 14; d++) fma4(q[rr][d], kv[d], s2);
      u[rr] += p0e(s1.x, s2.x, e1r[rr], e2r[rr]) * cv.x;
      u[rr] += p0e(s1.y, s2.y, e1r[rr], e2r[rr]) * cv.y;
      u[rr] += p0e(s1.z, s2.z, e1r[rr], e2r[rr]) * cv.z;
      u[rr] += p0e(s1.w, s2.w, e1r[rr], e2r[rr]) * cv.w;
    }
  }
#pragma unroll
  for (int rr = 0; rr < 4; rr++) u[rr] = wave_sum(u[rr]);
  if (lane == 0) {
#pragma unroll
    for (int rr = 0; rr < 4; rr++) {
      int o = b * 1024 + i0 + rr;
      float rv = R[o];
      rv = rv / fmaf(rv, u[rr], EPSF);
      R[o] = fminf(rv, 1e37f);
    }
  }
}

// ---------------- Sinkhorn pass B: v = P0^T @ R, update C ----------------
__global__ __launch_bounds__(512) void sinkB_kernel(
    const float* __restrict__ Qt, const float* __restrict__ Kt,
    const float* __restrict__ E1, const float* __restrict__ E2,
    const float* __restrict__ R, float* __restrict__ C) {
  __shared__ float4 Ql[3584];
  int b = blockIdx.x >> 5, blk = blockIdx.x & 31;
  int tid = threadIdx.x;
  const float4* Qtb = (const float4*)(Qt + b * 14336);
  for (int idx = tid; idx < 3584; idx += 512) Ql[idx] = Qtb[idx];
  __syncthreads();

  int wave = tid >> 6, lane = tid & 63;
  int j0 = blk * 32 + wave * 4;
  float kk[4][14], v[4];
#pragma unroll
  for (int rr = 0; rr < 4; rr++) {
#pragma unroll
    for (int d = 0; d < 14; d++) kk[rr][d] = Kt[b * 14336 + d * 1024 + j0 + rr];
    v[rr] = 0.f;
  }
  const float4* E1b = (const float4*)(E1 + b * 1024);
  const float4* E2b = (const float4*)(E2 + b * 1024);
  const float4* Rb  = (const float4*)(R + b * 1024);
#pragma unroll
  for (int t = 0; t < 4; t++) {
    int g = t * 64 + lane;
    float4 qv[14];
#pragma unroll
    for (int d = 0; d < 14; d++) qv[d] = Ql[d * 256 + g];
    float4 e1v = E1b[g], e2v = E2b[g], rv = Rb[g];
#pragma unroll
    for (int rr = 0; rr < 4; rr++) {
      float4 s1 = {0, 0, 0, 0}, s2 = {0, 0, 0, 0};
#pragma unroll
      for (int d = 0; d < 7; d++)  fma4(kk[rr][d], qv[d], s1);
#pragma unroll
      for (int d = 7; d < 14; d++) fma4(kk[rr][d], qv[d], s2);
      v[rr] += p0e(s1.x, s2.x, e1v.x, e2v.x) * rv.x;
      v[rr] += p0e(s1.y, s2.y, e1v.y, e2v.y) * rv.y;
      v[rr] += p0e(s1.z, s2.z, e1v.z, e2v.z) * rv.z;
      v[rr] += p0e(s1.w, s2.w, e1v.w, e2v.w) * rv.w;
    }
  }
#pragma unroll
  for (int rr = 0; rr < 4; rr++) v[rr] = wave_sum(v[rr]);
  if (lane == 0) {
#pragma unroll
    for (int rr = 0; rr < 4; rr++) {
      int o = b * 1024 + j0 + rr;
      float cv = C[o];
      cv = cv / fmaf(cv, v[rr], EPSF);
      C[o] = fminf(cv, 1e37f);
    }
  }
}

// ---------------- final argmax over P0_ij * C_j + permutation gather ----------------
// round-1 proven shape: 8192 blocks, 8 rows/block (one per wave)
__global__ __launch_bounds__(512) void argmax_kernel(
    const float* __restrict__ Qt, const float* __restrict__ Kt,
    const float* __restrict__ E1, const float* __restrict__ E2,
    const float* __restrict__ C, const int* __restrict__ perm,
    float* __restrict__ perm_out) {
  __shared__ float4 Kl[3584];
  int b = blockIdx.x >> 7, rg = blockIdx.x & 127;
  int tid = threadIdx.x;
  const float4* Ktb = (const float4*)(Kt + b * 14336);
  for (int idx = tid; idx < 3584; idx += 512) Kl[idx] = Ktb[idx];
  __syncthreads();

  int wave = tid >> 6, lane = tid & 63;
  int i = rg * 8 + wave;
  int row = b * 1024 + i;
  float q[14];
#pragma unroll
  for (int d = 0; d < 14; d++) q[d] = Qt[b * 14336 + d * 1024 + i];
  float e1r = E1[row], e2r = E2[row];
  const float4* Cb = (const float4*)(C + b * 1024);

  float best = -1.0f;
  int bj = 0;
#pragma unroll
  for (int t = 0; t < 4; t++) {
    int g = t * 64 + lane;
    float4 kv[14];
#pragma unroll
    for (int d = 0; d < 14; d++) kv[d] = Kl[d * 256 + g];
    float4 cv = Cb[g];
    float4 s1 = {0, 0, 0, 0}, s2 = {0, 0, 0, 0};
#pragma unroll
    for (int d = 0; d < 7; d++)  fma4(q[d], kv[d], s1);
#pragma unroll
    for (int d = 7; d < 14; d++) fma4(q[d], kv[d], s2);
    float val;
    val = p0e(s1.x, s2.x, e1r, e2r) * cv.x; if (val > best) { best = val; bj = 4 * g + 0; }
    val = p0e(s1.y, s2.y, e1r, e2r) * cv.y; if (val > best) { best = val; bj = 4 * g + 1; }
    val = p0e(s1.z, s2.z, e1r, e2r) * cv.z; if (val > best) { best = val; bj = 4 * g + 2; }
    val = p0e(s1.w, s2.w, e1r, e2r) * cv.w; if (val > best) { best = val; bj = 4 * g + 3; }
  }
  // cross-lane argmax, first-index tie-break
#pragma unroll
  for (int off = 32; off > 0; off >>= 1) {
    float ob = __shfl_xor(best, off);
    int oj = __shfl_xor(bj, off);
    if (ob > best || (ob == best && oj < bj)) { best = ob; bj = oj; }
  }
  if (lane == 0) perm_out[row] = (float)perm[b * 1024 + bj];
}

// ---------------- launch ----------------
extern "C" void kernel_launch(void* const* d_in, const int* in_sizes, int n_in,
                              void* d_out, int out_size, void* d_ws, size_t ws_size,
                              hipStream_t stream) {
  const float* x    = (const float*)d_in[0];
  const float* cert = (const float*)d_in[1];
  const int*   perm = (const int*)d_in[2];
  const float* Wq = (const float*)d_in[3];
  const float* bq = (const float*)d_in[4];
  const float* Wk = (const float*)d_in[5];
  const float* bk = (const float*)d_in[6];
  const float* Wv = (const float*)d_in[7];
  const float* bv = (const float*)d_in[8];
  const float* Wo = (const float*)d_in[9];
  const float* bo = (const float*)d_in[10];

  float* out      = (float*)d_out;            // 917504
  float* cert_out = out + 917504;             // 65536
  float* perm_out = out + 983040;             // 65536

  float* ws = (float*)d_ws;
  float* Qt = ws;                    // 917504
  float* Kt = Qt + 917504;           // 917504
  float* Vt = Kt + 917504;           // 917504
  float* E1 = Vt + 917504;           // 65536
  float* E2 = E1 + 65536;            // 65536
  float* R  = E2 + 65536;            // 65536
  float* C  = R + 65536;             // 65536
  float* attn_o = C + 65536;         // 917504  (total ~15.7 MB)

  qkv_kernel<<<256, 256, 0, stream>>>(x, Wq, bq, Wk, bk, Wv, bv, Qt, Kt, Vt, R, C);
  attn_kernel<<<4096, 1024, 0, stream>>>(Qt, Kt, Vt, cert, E1, E2, attn_o, cert_out);
  proj_kernel<<<3584, 256, 0, stream>>>(attn_o, Wo, bo, out);
  for (int it = 0; it < 20; it++) {
    sinkA_kernel<<<2048, 512, 0, stream>>>(Qt, Kt, E1, E2, C, R);
    sinkB_kernel<<<2048, 512, 0, stream>>>(Qt, Kt, E1, E2, R, C);
  }
  argmax_kernel<<<8192, 512, 0, stream>>>(Qt, Kt, E1, E2, C, perm, perm_out);
}

// Round 4
// 2938.878 us; speedup vs baseline: 1.8357x; 1.0038x over previous
//
#include <hip/hip_runtime.h>

#define EPSF    1e-10f
#define MAXENT  6.93147180559945286f   // ln(1024)
#define SCALEF  0.37796447300922720f   // 1/sqrt(7)

// ---------------- helpers ----------------
__device__ __forceinline__ float wave_sum(float v) {
#pragma unroll
  for (int off = 32; off > 0; off >>= 1) v += __shfl_xor(v, off);
  return v;
}
__device__ __forceinline__ void fma4(float a, float4 b, float4& c) {
  c.x = fmaf(a, b.x, c.x); c.y = fmaf(a, b.y, c.y);
  c.z = fmaf(a, b.z, c.z); c.w = fmaf(a, b.w, c.w);
}
__device__ __forceinline__ float exp4sum(float4 s) {
  return __expf(s.x) + __expf(s.y) + __expf(s.z) + __expf(s.w);
}
// P0 = (E1*exp(s1) + E2*exp(s2) + EPS)^10, E_h = 0.5/L_h (no-max softmax; |s|<~12 so safe)
__device__ __forceinline__ float p0e(float s1, float s2, float E1, float E2) {
  float p = fmaf(E1, __expf(s1), fmaf(E2, __expf(s2), EPSF));
  float p2 = p * p, p4 = p2 * p2, p5 = p4 * p;
  return p5 * p5;
}

// ---------------- kernel 0: QKV projection (d-major, Q pre-scaled) + R/C/v init ----------------
__global__ __launch_bounds__(256) void qkv_kernel(
    const float* __restrict__ x,
    const float* __restrict__ Wq, const float* __restrict__ bq,
    const float* __restrict__ Wk, const float* __restrict__ bk,
    const float* __restrict__ Wv, const float* __restrict__ bv,
    float* __restrict__ Qt, float* __restrict__ Kt, float* __restrict__ Vt,
    float* __restrict__ R, float* __restrict__ C, float* __restrict__ vg) {
  int row = blockIdx.x * 256 + threadIdx.x;     // 65536 rows
  int b = row >> 10, i = row & 1023;
  float xv[14];
#pragma unroll
  for (int k = 0; k < 14; k++) xv[k] = x[row * 14 + k];
#pragma unroll
  for (int d = 0; d < 14; d++) {
    float q = bq[d], kk = bk[d], vv = bv[d];
#pragma unroll
    for (int k = 0; k < 14; k++) {
      q  = fmaf(xv[k], Wq[d * 14 + k], q);
      kk = fmaf(xv[k], Wk[d * 14 + k], kk);
      vv = fmaf(xv[k], Wv[d * 14 + k], vv);
    }
    int o = b * 14336 + d * 1024 + i;
    Qt[o] = q * SCALEF;
    Kt[o] = kk; Vt[o] = vv;
  }
  R[row] = 1.0f;
  C[row] = 1.0f;
  if (vg) vg[row] = 0.0f;
}

// ---------------- kernel 1: fused attention + entropy/certainty + E1/E2 ----------------
// 512 thr = 8 waves x 2 rows = 16 rows/block; K in LDS (stays resident), V read from
// global in pass 2; NO stored score registers (round-2/3 spill source), no max-subtract.
__global__ __launch_bounds__(512) void attn_kernel(
    const float* __restrict__ Qt, const float* __restrict__ Kt, const float* __restrict__ Vt,
    const float* __restrict__ cert_in,
    float* __restrict__ E1o, float* __restrict__ E2o,
    float* __restrict__ attn_o, float* __restrict__ cert_out) {
  __shared__ float4 Kl[3584];                   // 56 KB
  int b = blockIdx.x >> 6;                      // 64 blocks per batch
  int rg = blockIdx.x & 63;                     // 16 rows per block
  int tid = threadIdx.x;
  const float4* Ktb = (const float4*)(Kt + b * 14336);
  for (int idx = tid; idx < 3584; idx += 512) Kl[idx] = Ktb[idx];
  __syncthreads();

  int wave = tid >> 6, lane = tid & 63;
  int i0 = rg * 16 + wave * 2;                  // two rows per wave
  float q0[14], q1[14];
#pragma unroll
  for (int d = 0; d < 14; d++) {
    q0[d] = Qt[b * 14336 + d * 1024 + i0];
    q1[d] = Qt[b * 14336 + d * 1024 + i0 + 1];
  }

  // pass 1: L_h = sum_j exp(s_h) per row per head
  float L10 = 0.f, L20 = 0.f, L11 = 0.f, L21 = 0.f;
#pragma unroll
  for (int t = 0; t < 4; t++) {
    int g = t * 64 + lane;
    float4 kv[7];
#pragma unroll
    for (int d = 0; d < 7; d++) kv[d] = Kl[d * 256 + g];
    float4 sa = {0,0,0,0}, sb = {0,0,0,0};
#pragma unroll
    for (int d = 0; d < 7; d++) { fma4(q0[d], kv[d], sa); fma4(q1[d], kv[d], sb); }
    L10 += exp4sum(sa); L11 += exp4sum(sb);
#pragma unroll
    for (int d = 0; d < 7; d++) kv[d] = Kl[(d + 7) * 256 + g];
    sa = make_float4(0,0,0,0); sb = make_float4(0,0,0,0);
#pragma unroll
    for (int d = 0; d < 7; d++) { fma4(q0[d + 7], kv[d], sa); fma4(q1[d + 7], kv[d], sb); }
    L20 += exp4sum(sa); L21 += exp4sum(sb);
  }
  L10 = wave_sum(L10); L20 = wave_sum(L20);
  L11 = wave_sum(L11); L21 = wave_sum(L21);
  float i10 = 1.0f / L10, i20 = 1.0f / L20, i11 = 1.0f / L11, i21 = 1.0f / L21;

  // pass 2: recompute scores, accumulate O and entropy
  float acc0[14], acc1[14];
#pragma unroll
  for (int d = 0; d < 14; d++) { acc0[d] = 0.f; acc1[d] = 0.f; }
  float ent0 = 0.f, ent1 = 0.f;
  const float4* Vtb = (const float4*)(Vt + b * 14336);
#pragma unroll
  for (int t = 0; t < 4; t++) {
    int g = t * 64 + lane;
    float4 kv[7];
#pragma unroll
    for (int d = 0; d < 7; d++) kv[d] = Kl[d * 256 + g];
    float4 sa = {0,0,0,0}, sb = {0,0,0,0};
#pragma unroll
    for (int d = 0; d < 7; d++) { fma4(q0[d], kv[d], sa); fma4(q1[d], kv[d], sb); }
    float4 e10 = make_float4(__expf(sa.x), __expf(sa.y), __expf(sa.z), __expf(sa.w));
    float4 e11 = make_float4(__expf(sb.x), __expf(sb.y), __expf(sb.z), __expf(sb.w));
#pragma unroll
    for (int d = 0; d < 7; d++) kv[d] = Kl[(d + 7) * 256 + g];
    sa = make_float4(0,0,0,0); sb = make_float4(0,0,0,0);
#pragma unroll
    for (int d = 0; d < 7; d++) { fma4(q0[d + 7], kv[d], sa); fma4(q1[d + 7], kv[d], sb); }
    float4 e20 = make_float4(__expf(sa.x), __expf(sa.y), __expf(sa.z), __expf(sa.w));
    float4 e21 = make_float4(__expf(sb.x), __expf(sb.y), __expf(sb.z), __expf(sb.w));
#pragma unroll
    for (int d = 0; d < 7; d++) {
      float4 vv = Vtb[d * 256 + g];
      acc0[d] += e10.x * vv.x + e10.y * vv.y + e10.z * vv.z + e10.w * vv.w;
      acc1[d] += e11.x * vv.x + e11.y * vv.y + e11.z * vv.z + e11.w * vv.w;
    }
#pragma unroll
    for (int d = 7; d < 14; d++) {
      float4 vv = Vtb[d * 256 + g];
      acc0[d] += e20.x * vv.x + e20.y * vv.y + e20.z * vv.z + e20.w * vv.w;
      acc1[d] += e21.x * vv.x + e21.y * vv.y + e21.z * vv.z + e21.w * vv.w;
    }
    float a;
    a = 0.5f * (e10.x * i10 + e20.x * i20); ent0 -= a * __logf(a + EPSF);
    a = 0.5f * (e10.y * i10 + e20.y * i20); ent0 -= a * __logf(a + EPSF);
    a = 0.5f * (e10.z * i10 + e20.z * i20); ent0 -= a * __logf(a + EPSF);
    a = 0.5f * (e10.w * i10 + e20.w * i20); ent0 -= a * __logf(a + EPSF);
    a = 0.5f * (e11.x * i11 + e21.x * i21); ent1 -= a * __logf(a + EPSF);
    a = 0.5f * (e11.y * i11 + e21.y * i21); ent1 -= a * __logf(a + EPSF);
    a = 0.5f * (e11.z * i11 + e21.z * i21); ent1 -= a * __logf(a + EPSF);
    a = 0.5f * (e11.w * i11 + e21.w * i21); ent1 -= a * __logf(a + EPSF);
  }
  ent0 = wave_sum(ent0); ent1 = wave_sum(ent1);
#pragma unroll
  for (int d = 0; d < 14; d++) { acc0[d] = wave_sum(acc0[d]); acc1[d] = wave_sum(acc1[d]); }

  if (lane == 0) {
    int row0 = b * 1024 + i0;
    E1o[row0] = 0.5f * i10;  E2o[row0] = 0.5f * i20;
    E1o[row0 + 1] = 0.5f * i11; E2o[row0 + 1] = 0.5f * i21;
#pragma unroll
    for (int d = 0; d < 14; d++) {
      attn_o[row0 * 14 + d] = acc0[d] * (d < 7 ? i10 : i20);
      attn_o[(row0 + 1) * 14 + d] = acc1[d] * (d < 7 ? i11 : i21);
    }
    cert_out[row0] = fmaxf(cert_in[row0], 1.0f / (1.0f + __expf(ent0 - MAXENT)));
    cert_out[row0 + 1] = fmaxf(cert_in[row0 + 1], 1.0f / (1.0f + __expf(ent1 - MAXENT)));
  }
}

// ---------------- kernel 2: output projection ----------------
__global__ __launch_bounds__(256) void proj_kernel(
    const float* __restrict__ attn_o, const float* __restrict__ Wo,
    const float* __restrict__ bo, float* __restrict__ out) {
  int idx = blockIdx.x * 256 + threadIdx.x;     // 917504 = 65536*14
  if (idx >= 917504) return;
  int row = idx / 14, d = idx - row * 14;
  float s = bo[d];
  const float* ar = attn_o + row * 14;
  const float* wr = Wo + d * 14;
#pragma unroll
  for (int k = 0; k < 14; k++) s = fmaf(ar[k], wr[k], s);
  out[idx] = s;
}

// ================= FAST PATH: materialized P0 =================

// ---------------- precompute P0 (once) ----------------
// 2048 blocks x 512 thr; 8 waves x 4 rows = 32 rows/block (round-3 sinkA structure)
__global__ __launch_bounds__(512) void p0pre_kernel(
    const float* __restrict__ Qt, const float* __restrict__ Kt,
    const float* __restrict__ E1, const float* __restrict__ E2,
    float* __restrict__ P0) {
  __shared__ float4 Kl[3584];
  int b = blockIdx.x >> 5, blk = blockIdx.x & 31;
  int tid = threadIdx.x;
  const float4* Ktb = (const float4*)(Kt + b * 14336);
  for (int idx = tid; idx < 3584; idx += 512) Kl[idx] = Ktb[idx];
  __syncthreads();

  int wave = tid >> 6, lane = tid & 63;
  int i0 = blk * 32 + wave * 4;
  float q[4][14], e1r[4], e2r[4];
#pragma unroll
  for (int rr = 0; rr < 4; rr++) {
#pragma unroll
    for (int d = 0; d < 14; d++) q[rr][d] = Qt[b * 14336 + d * 1024 + i0 + rr];
    e1r[rr] = E1[b * 1024 + i0 + rr];
    e2r[rr] = E2[b * 1024 + i0 + rr];
  }
  float4* P0f4 = (float4*)P0;
#pragma unroll
  for (int t = 0; t < 4; t++) {
    int g = t * 64 + lane;
    float4 kv[14];
#pragma unroll
    for (int d = 0; d < 14; d++) kv[d] = Kl[d * 256 + g];
#pragma unroll
    for (int rr = 0; rr < 4; rr++) {
      float4 s1 = {0,0,0,0}, s2 = {0,0,0,0};
#pragma unroll
      for (int d = 0; d < 7; d++)  fma4(q[rr][d], kv[d], s1);
#pragma unroll
      for (int d = 7; d < 14; d++) fma4(q[rr][d], kv[d], s2);
      float4 pv;
      pv.x = p0e(s1.x, s2.x, e1r[rr], e2r[rr]);
      pv.y = p0e(s1.y, s2.y, e1r[rr], e2r[rr]);
      pv.z = p0e(s1.z, s2.z, e1r[rr], e2r[rr]);
      pv.w = p0e(s1.w, s2.w, e1r[rr], e2r[rr]);
      P0f4[((size_t)(b * 1024 + i0 + rr)) * 256 + g] = pv;
    }
  }
}

// ---------------- fused Sinkhorn iteration: u=P0.C, R update, v += R'.P0 ----------------
// 1024 blocks (64 b x 16), 512 thr = 8 waves; each wave 8 rows, row in 16 VGPRs.
__global__ __launch_bounds__(512) void sink_fused(
    const float* __restrict__ P0, const float* __restrict__ Cg,
    float* __restrict__ R, float* __restrict__ vg) {
  __shared__ float vbuf[1024];
  int tid = threadIdx.x;
  for (int idx = tid; idx < 1024; idx += 512) vbuf[idx] = 0.f;
  int b = blockIdx.x >> 4, rb = blockIdx.x & 15;
  int wave = tid >> 6, lane = tid & 63;
  const float4* Cb = (const float4*)(Cg + b * 1024);
  float4 c0 = Cb[lane], c1 = Cb[64 + lane], c2 = Cb[128 + lane], c3 = Cb[192 + lane];
  float4 v0 = {0,0,0,0}, v1 = {0,0,0,0}, v2 = {0,0,0,0}, v3 = {0,0,0,0};
  __syncthreads();

  int i0 = rb * 64 + wave * 8;
  const float4* P0f4 = (const float4*)P0;
  for (int r = 0; r < 8; r++) {
    int row = b * 1024 + i0 + r;
    const float4* Prow = P0f4 + (size_t)row * 256;
    float4 p0 = Prow[lane], p1 = Prow[64 + lane], p2 = Prow[128 + lane], p3 = Prow[192 + lane];
    float u = p0.x * c0.x;
    u = fmaf(p0.y, c0.y, u); u = fmaf(p0.z, c0.z, u); u = fmaf(p0.w, c0.w, u);
    u = fmaf(p1.x, c1.x, u); u = fmaf(p1.y, c1.y, u); u = fmaf(p1.z, c1.z, u); u = fmaf(p1.w, c1.w, u);
    u = fmaf(p2.x, c2.x, u); u = fmaf(p2.y, c2.y, u); u = fmaf(p2.z, c2.z, u); u = fmaf(p2.w, c2.w, u);
    u = fmaf(p3.x, c3.x, u); u = fmaf(p3.y, c3.y, u); u = fmaf(p3.z, c3.z, u); u = fmaf(p3.w, c3.w, u);
    u = wave_sum(u);
    float rv = R[row];
    rv = fminf(rv / fmaf(rv, u, EPSF), 1e37f);
    if (lane == 0) R[row] = rv;
    fma4(rv, p0, v0); fma4(rv, p1, v1); fma4(rv, p2, v2); fma4(rv, p3, v3);
  }
  // merge per-wave v partials into LDS
  atomicAdd(&vbuf[4 * lane + 0], v0.x); atomicAdd(&vbuf[4 * lane + 1], v0.y);
  atomicAdd(&vbuf[4 * lane + 2], v0.z); atomicAdd(&vbuf[4 * lane + 3], v0.w);
  atomicAdd(&vbuf[256 + 4 * lane + 0], v1.x); atomicAdd(&vbuf[256 + 4 * lane + 1], v1.y);
  atomicAdd(&vbuf[256 + 4 * lane + 2], v1.z); atomicAdd(&vbuf[256 + 4 * lane + 3], v1.w);
  atomicAdd(&vbuf[512 + 4 * lane + 0], v2.x); atomicAdd(&vbuf[512 + 4 * lane + 1], v2.y);
  atomicAdd(&vbuf[512 + 4 * lane + 2], v2.z); atomicAdd(&vbuf[512 + 4 * lane + 3], v2.w);
  atomicAdd(&vbuf[768 + 4 * lane + 0], v3.x); atomicAdd(&vbuf[768 + 4 * lane + 1], v3.y);
  atomicAdd(&vbuf[768 + 4 * lane + 2], v3.z); atomicAdd(&vbuf[768 + 4 * lane + 3], v3.w);
  __syncthreads();
  for (int idx = tid; idx < 1024; idx += 512)
    atomicAdd(&vg[b * 1024 + idx], vbuf[idx]);
}

// ---------------- C update + v re-zero ----------------
__global__ __launch_bounds__(256) void cupdate_kernel(float* __restrict__ C,
                                                      float* __restrict__ vg) {
  int idx = blockIdx.x * 256 + threadIdx.x;     // 65536
  float cv = C[idx], vv = vg[idx];
  C[idx] = fminf(cv / fmaf(cv, vv, EPSF), 1e37f);
  vg[idx] = 0.f;
}

// ---------------- argmax over stored P0 * C + permutation gather ----------------
__global__ __launch_bounds__(512) void argmaxP_kernel(
    const float* __restrict__ P0, const float* __restrict__ Cg,
    const int* __restrict__ perm, float* __restrict__ perm_out) {
  int b = blockIdx.x >> 7, rg = blockIdx.x & 127;
  int tid = threadIdx.x;
  int wave = tid >> 6, lane = tid & 63;
  int i = rg * 8 + wave;
  int row = b * 1024 + i;
  const float4* Cb = (const float4*)(Cg + b * 1024);
  const float4* Prow = (const float4*)P0 + (size_t)row * 256;

  float best = -1.0f;
  int bj = 0;
#pragma unroll
  for (int t = 0; t < 4; t++) {
    int g = t * 64 + lane;
    float4 pv = Prow[g], cv = Cb[g];
    float val;
    val = pv.x * cv.x; if (val > best) { best = val; bj = 4 * g + 0; }
    val = pv.y * cv.y; if (val > best) { best = val; bj = 4 * g + 1; }
    val = pv.z * cv.z; if (val > best) { best = val; bj = 4 * g + 2; }
    val = pv.w * cv.w; if (val > best) { best = val; bj = 4 * g + 3; }
  }
#pragma unroll
  for (int off = 32; off > 0; off >>= 1) {
    float ob = __shfl_xor(best, off);
    int oj = __shfl_xor(bj, off);
    if (ob > best || (ob == best && oj < bj)) { best = ob; bj = oj; }
  }
  if (lane == 0) perm_out[row] = (float)perm[b * 1024 + bj];
}

// ================= FALLBACK PATH (round-3, recompute) =================

__global__ __launch_bounds__(512) void sinkA_kernel(
    const float* __restrict__ Qt, const float* __restrict__ Kt,
    const float* __restrict__ E1, const float* __restrict__ E2,
    const float* __restrict__ C, float* __restrict__ R) {
  __shared__ float4 Kl[3584];
  int b = blockIdx.x >> 5, blk = blockIdx.x & 31;
  int tid = threadIdx.x;
  const float4* Ktb = (const float4*)(Kt + b * 14336);
  for (int idx = tid; idx < 3584; idx += 512) Kl[idx] = Ktb[idx];
  __syncthreads();
  int wave = tid >> 6, lane = tid & 63;
  int i0 = blk * 32 + wave * 4;
  float q[4][14], e1r[4], e2r[4], u[4];
#pragma unroll
  for (int rr = 0; rr < 4; rr++) {
#pragma unroll
    for (int d = 0; d < 14; d++) q[rr][d] = Qt[b * 14336 + d * 1024 + i0 + rr];
    e1r[rr] = E1[b * 1024 + i0 + rr];
    e2r[rr] = E2[b * 1024 + i0 + rr];
    u[rr] = 0.f;
  }
  const float4* Cb = (const float4*)(C + b * 1024);
#pragma unroll
  for (int t = 0; t < 4; t++) {
    int g = t * 64 + lane;
    float4 kv[14];
#pragma unroll
    for (int d = 0; d < 14; d++) kv[d] = Kl[d * 256 + g];
    float4 cv = Cb[g];
#pragma unroll
    for (int rr = 0; rr < 4; rr++) {
      float4 s1 = {0,0,0,0}, s2 = {0,0,0,0};
#pragma unroll
      for (int d = 0; d < 7; d++)  fma4(q[rr][d], kv[d], s1);
#pragma unroll
      for (int d = 7; d < 14; d++) fma4(q[rr][d], kv[d], s2);
      u[rr] += p0e(s1.x, s2.x, e1r[rr], e2r[rr]) * cv.x;
      u[rr] += p0e(s1.y, s2.y, e1r[rr], e2r[rr]) * cv.y;
      u[rr] += p0e(s1.z, s2.z, e1r[rr], e2r[rr]) * cv.z;
      u[rr] += p0e(s1.w, s2.w, e1r[rr], e2r[rr]) * cv.w;
    }
  }
#pragma unroll
  for (int rr = 0; rr < 4; rr++) u[rr] = wave_sum(u[rr]);
  if (lane == 0) {
#pragma unroll
    for (int rr = 0; rr < 4; rr++) {
      int o = b * 1024 + i0 + rr;
      float rv = R[o];
      R[o] = fminf(rv / fmaf(rv, u[rr], EPSF), 1e37f);
    }
  }
}

__global__ __launch_bounds__(512) void sinkB_kernel(
    const float* __restrict__ Qt, const float* __restrict__ Kt,
    const float* __restrict__ E1, const float* __restrict__ E2,
    const float* __restrict__ R, float* __restrict__ C) {
  __shared__ float4 Ql[3584];
  int b = blockIdx.x >> 5, blk = blockIdx.x & 31;
  int tid = threadIdx.x;
  const float4* Qtb = (const float4*)(Qt + b * 14336);
  for (int idx = tid; idx < 3584; idx += 512) Ql[idx] = Qtb[idx];
  __syncthreads();
  int wave = tid >> 6, lane = tid & 63;
  int j0 = blk * 32 + wave * 4;
  float kk[4][14], v[4];
#pragma unroll
  for (int rr = 0; rr < 4; rr++) {
#pragma unroll
    for (int d = 0; d < 14; d++) kk[rr][d] = Kt[b * 14336 + d * 1024 + j0 + rr];
    v[rr] = 0.f;
  }
  const float4* E1b = (const float4*)(E1 + b * 1024);
  const float4* E2b = (const float4*)(E2 + b * 1024);
  const float4* Rb  = (const float4*)(R + b * 1024);
#pragma unroll
  for (int t = 0; t < 4; t++) {
    int g = t * 64 + lane;
    float4 qv[14];
#pragma unroll
    for (int d = 0; d < 14; d++) qv[d] = Ql[d * 256 + g];
    float4 e1v = E1b[g], e2v = E2b[g], rv = Rb[g];
#pragma unroll
    for (int rr = 0; rr < 4; rr++) {
      float4 s1 = {0,0,0,0}, s2 = {0,0,0,0};
#pragma unroll
      for (int d = 0; d < 7; d++)  fma4(kk[rr][d], qv[d], s1);
#pragma unroll
      for (int d = 7; d < 14; d++) fma4(kk[rr][d], qv[d], s2);
      v[rr] += p0e(s1.x, s2.x, e1v.x, e2v.x) * rv.x;
      v[rr] += p0e(s1.y, s2.y, e1v.y, e2v.y) * rv.y;
      v[rr] += p0e(s1.z, s2.z, e1v.z, e2v.z) * rv.z;
      v[rr] += p0e(s1.w, s2.w, e1v.w, e2v.w) * rv.w;
    }
  }
#pragma unroll
  for (int rr = 0; rr < 4; rr++) v[rr] = wave_sum(v[rr]);
  if (lane == 0) {
#pragma unroll
    for (int rr = 0; rr < 4; rr++) {
      int o = b * 1024 + j0 + rr;
      float cv = C[o];
      C[o] = fminf(cv / fmaf(cv, v[rr], EPSF), 1e37f);
    }
  }
}

__global__ __launch_bounds__(512) void argmax_kernel(
    const float* __restrict__ Qt, const float* __restrict__ Kt,
    const float* __restrict__ E1, const float* __restrict__ E2,
    const float* __restrict__ C, const int* __restrict__ perm,
    float* __restrict__ perm_out) {
  __shared__ float4 Kl[3584];
  int b = blockIdx.x >> 7, rg = blockIdx.x & 127;
  int tid = threadIdx.x;
  const float4* Ktb = (const float4*)(Kt + b * 14336);
  for (int idx = tid; idx < 3584; idx += 512) Kl[idx] = Ktb[idx];
  __syncthreads();
  int wave = tid >> 6, lane = tid & 63;
  int i = rg * 8 + wave;
  int row = b * 1024 + i;
  float q[14];
#pragma unroll
  for (int d = 0; d < 14; d++) q[d] = Qt[b * 14336 + d * 1024 + i];
  float e1r = E1[row], e2r = E2[row];
  const float4* Cb = (const float4*)(C + b * 1024);
  float best = -1.0f;
  int bj = 0;
#pragma unroll
  for (int t = 0; t < 4; t++) {
    int g = t * 64 + lane;
    float4 kv[14];
#pragma unroll
    for (int d = 0; d < 14; d++) kv[d] = Kl[d * 256 + g];
    float4 cv = Cb[g];
    float4 s1 = {0,0,0,0}, s2 = {0,0,0,0};
#pragma unroll
    for (int d = 0; d < 7; d++)  fma4(q[d], kv[d], s1);
#pragma unroll
    for (int d = 7; d < 14; d++) fma4(q[d], kv[d], s2);
    float val;
    val = p0e(s1.x, s2.x, e1r, e2r) * cv.x; if (val > best) { best = val; bj = 4 * g + 0; }
    val = p0e(s1.y, s2.y, e1r, e2r) * cv.y; if (val > best) { best = val; bj = 4 * g + 1; }
    val = p0e(s1.z, s2.z, e1r, e2r) * cv.z; if (val > best) { best = val; bj = 4 * g + 2; }
    val = p0e(s1.w, s2.w, e1r, e2r) * cv.w; if (val > best) { best = val; bj = 4 * g + 3; }
  }
#pragma unroll
  for (int off = 32; off > 0; off >>= 1) {
    float ob = __shfl_xor(best, off);
    int oj = __shfl_xor(bj, off);
    if (ob > best || (ob == best && oj < bj)) { best = ob; bj = oj; }
  }
  if (lane == 0) perm_out[row] = (float)perm[b * 1024 + bj];
}

// ---------------- launch ----------------
extern "C" void kernel_launch(void* const* d_in, const int* in_sizes, int n_in,
                              void* d_out, int out_size, void* d_ws, size_t ws_size,
                              hipStream_t stream) {
  const float* x    = (const float*)d_in[0];
  const float* cert = (const float*)d_in[1];
  const int*   perm = (const int*)d_in[2];
  const float* Wq = (const float*)d_in[3];
  const float* bq = (const float*)d_in[4];
  const float* Wk = (const float*)d_in[5];
  const float* bk = (const float*)d_in[6];
  const float* Wv = (const float*)d_in[7];
  const float* bv = (const float*)d_in[8];
  const float* Wo = (const float*)d_in[9];
  const float* bo = (const float*)d_in[10];

  float* out      = (float*)d_out;            // 917504
  float* cert_out = out + 917504;             // 65536
  float* perm_out = out + 983040;             // 65536

  float* ws = (float*)d_ws;
  float* Qt = ws;                    // 917504
  float* Kt = Qt + 917504;           // 917504
  float* Vt = Kt + 917504;           // 917504
  float* E1 = Vt + 917504;           // 65536
  float* E2 = E1 + 65536;            // 65536
  float* R  = E2 + 65536;            // 65536
  float* C  = R + 65536;             // 65536
  float* vg = C + 65536;             // 65536
  float* attn_o = vg + 65536;        // 917504
  float* P0 = attn_o + 917504;       // 67108864 (256 MB)
  const size_t need_fast = (size_t)(3997696 + 67108864) * 4;  // ~284.4 MB

  bool fast = ws_size >= need_fast;

  qkv_kernel<<<256, 256, 0, stream>>>(x, Wq, bq, Wk, bk, Wv, bv, Qt, Kt, Vt, R, C,
                                      fast ? vg : nullptr);
  attn_kernel<<<4096, 512, 0, stream>>>(Qt, Kt, Vt, cert, E1, E2, attn_o, cert_out);
  proj_kernel<<<3584, 256, 0, stream>>>(attn_o, Wo, bo, out);

  if (fast) {
    p0pre_kernel<<<2048, 512, 0, stream>>>(Qt, Kt, E1, E2, P0);
    for (int it = 0; it < 20; it++) {
      sink_fused<<<1024, 512, 0, stream>>>(P0, C, R, vg);
      cupdate_kernel<<<256, 256, 0, stream>>>(C, vg);
    }
    argmaxP_kernel<<<8192, 512, 0, stream>>>(P0, C, perm, perm_out);
  } else {
    for (int it = 0; it < 20; it++) {
      sinkA_kernel<<<2048, 512, 0, stream>>>(Qt, Kt, E1, E2, C, R);
      sinkB_kernel<<<2048, 512, 0, stream>>>(Qt, Kt, E1, E2, R, C);
    }
    argmax_kernel<<<8192, 512, 0, stream>>>(Qt, Kt, E1, E2, C, perm, perm_out);
  }
}

// Round 5
// 2317.503 us; speedup vs baseline: 2.3278x; 1.2681x over previous
//
#include <hip/hip_runtime.h>

#define EPSF    1e-10f
#define MAXENT  6.93147180559945286f   // ln(1024)
#define SCALEF  0.37796447300922720f   // 1/sqrt(7)

// ---------------- helpers ----------------
__device__ __forceinline__ float wave_sum(float v) {
#pragma unroll
  for (int off = 32; off > 0; off >>= 1) v += __shfl_xor(v, off);
  return v;
}
__device__ __forceinline__ void fma4(float a, float4 b, float4& c) {
  c.x = fmaf(a, b.x, c.x); c.y = fmaf(a, b.y, c.y);
  c.z = fmaf(a, b.z, c.z); c.w = fmaf(a, b.w, c.w);
}
__device__ __forceinline__ float exp4sum(float4 s) {
  return __expf(s.x) + __expf(s.y) + __expf(s.z) + __expf(s.w);
}
// P0 = (E1*exp(s1) + E2*exp(s2) + EPS)^10, E_h = 0.5/L_h (no-max softmax; |s|<~12 so safe)
__device__ __forceinline__ float p0e(float s1, float s2, float E1, float E2) {
  float p = fmaf(E1, __expf(s1), fmaf(E2, __expf(s2), EPSF));
  float p2 = p * p, p4 = p2 * p2, p5 = p4 * p;
  return p5 * p5;
}

// ---------------- kernel 0: QKV projection (d-major, Q pre-scaled) + R/C init ----------------
__global__ __launch_bounds__(256) void qkv_kernel(
    const float* __restrict__ x,
    const float* __restrict__ Wq, const float* __restrict__ bq,
    const float* __restrict__ Wk, const float* __restrict__ bk,
    const float* __restrict__ Wv, const float* __restrict__ bv,
    float* __restrict__ Qt, float* __restrict__ Kt, float* __restrict__ Vt,
    float* __restrict__ R, float* __restrict__ C) {
  int row = blockIdx.x * 256 + threadIdx.x;     // 65536 rows
  int b = row >> 10, i = row & 1023;
  float xv[14];
#pragma unroll
  for (int k = 0; k < 14; k++) xv[k] = x[row * 14 + k];
#pragma unroll
  for (int d = 0; d < 14; d++) {
    float q = bq[d], kk = bk[d], vv = bv[d];
#pragma unroll
    for (int k = 0; k < 14; k++) {
      q  = fmaf(xv[k], Wq[d * 14 + k], q);
      kk = fmaf(xv[k], Wk[d * 14 + k], kk);
      vv = fmaf(xv[k], Wv[d * 14 + k], vv);
    }
    int o = b * 14336 + d * 1024 + i;
    Qt[o] = q * SCALEF;
    Kt[o] = kk; Vt[o] = vv;
  }
  R[row] = 1.0f;
  C[row] = 1.0f;
}

// ---------------- kernel 1: fused attention + entropy/certainty + E1/E2 ----------------
// 512 thr = 8 waves x 2 rows = 16 rows/block; K in LDS, V from global in pass 2.
__global__ __launch_bounds__(512) void attn_kernel(
    const float* __restrict__ Qt, const float* __restrict__ Kt, const float* __restrict__ Vt,
    const float* __restrict__ cert_in,
    float* __restrict__ E1o, float* __restrict__ E2o,
    float* __restrict__ attn_o, float* __restrict__ cert_out) {
  __shared__ float4 Kl[3584];                   // 56 KB
  int b = blockIdx.x >> 6;
  int rg = blockIdx.x & 63;
  int tid = threadIdx.x;
  const float4* Ktb = (const float4*)(Kt + b * 14336);
  for (int idx = tid; idx < 3584; idx += 512) Kl[idx] = Ktb[idx];
  __syncthreads();

  int wave = tid >> 6, lane = tid & 63;
  int i0 = rg * 16 + wave * 2;
  float q0[14], q1[14];
#pragma unroll
  for (int d = 0; d < 14; d++) {
    q0[d] = Qt[b * 14336 + d * 1024 + i0];
    q1[d] = Qt[b * 14336 + d * 1024 + i0 + 1];
  }

  float L10 = 0.f, L20 = 0.f, L11 = 0.f, L21 = 0.f;
#pragma unroll
  for (int t = 0; t < 4; t++) {
    int g = t * 64 + lane;
    float4 kv[7];
#pragma unroll
    for (int d = 0; d < 7; d++) kv[d] = Kl[d * 256 + g];
    float4 sa = {0,0,0,0}, sb = {0,0,0,0};
#pragma unroll
    for (int d = 0; d < 7; d++) { fma4(q0[d], kv[d], sa); fma4(q1[d], kv[d], sb); }
    L10 += exp4sum(sa); L11 += exp4sum(sb);
#pragma unroll
    for (int d = 0; d < 7; d++) kv[d] = Kl[(d + 7) * 256 + g];
    sa = make_float4(0,0,0,0); sb = make_float4(0,0,0,0);
#pragma unroll
    for (int d = 0; d < 7; d++) { fma4(q0[d + 7], kv[d], sa); fma4(q1[d + 7], kv[d], sb); }
    L20 += exp4sum(sa); L21 += exp4sum(sb);
  }
  L10 = wave_sum(L10); L20 = wave_sum(L20);
  L11 = wave_sum(L11); L21 = wave_sum(L21);
  float i10 = 1.0f / L10, i20 = 1.0f / L20, i11 = 1.0f / L11, i21 = 1.0f / L21;

  float acc0[14], acc1[14];
#pragma unroll
  for (int d = 0; d < 14; d++) { acc0[d] = 0.f; acc1[d] = 0.f; }
  float ent0 = 0.f, ent1 = 0.f;
  const float4* Vtb = (const float4*)(Vt + b * 14336);
#pragma unroll
  for (int t = 0; t < 4; t++) {
    int g = t * 64 + lane;
    float4 kv[7];
#pragma unroll
    for (int d = 0; d < 7; d++) kv[d] = Kl[d * 256 + g];
    float4 sa = {0,0,0,0}, sb = {0,0,0,0};
#pragma unroll
    for (int d = 0; d < 7; d++) { fma4(q0[d], kv[d], sa); fma4(q1[d], kv[d], sb); }
    float4 e10 = make_float4(__expf(sa.x), __expf(sa.y), __expf(sa.z), __expf(sa.w));
    float4 e11 = make_float4(__expf(sb.x), __expf(sb.y), __expf(sb.z), __expf(sb.w));
#pragma unroll
    for (int d = 0; d < 7; d++) kv[d] = Kl[(d + 7) * 256 + g];
    sa = make_float4(0,0,0,0); sb = make_float4(0,0,0,0);
#pragma unroll
    for (int d = 0; d < 7; d++) { fma4(q0[d + 7], kv[d], sa); fma4(q1[d + 7], kv[d], sb); }
    float4 e20 = make_float4(__expf(sa.x), __expf(sa.y), __expf(sa.z), __expf(sa.w));
    float4 e21 = make_float4(__expf(sb.x), __expf(sb.y), __expf(sb.z), __expf(sb.w));
#pragma unroll
    for (int d = 0; d < 7; d++) {
      float4 vv = Vtb[d * 256 + g];
      acc0[d] += e10.x * vv.x + e10.y * vv.y + e10.z * vv.z + e10.w * vv.w;
      acc1[d] += e11.x * vv.x + e11.y * vv.y + e11.z * vv.z + e11.w * vv.w;
    }
#pragma unroll
    for (int d = 7; d < 14; d++) {
      float4 vv = Vtb[d * 256 + g];
      acc0[d] += e20.x * vv.x + e20.y * vv.y + e20.z * vv.z + e20.w * vv.w;
      acc1[d] += e21.x * vv.x + e21.y * vv.y + e21.z * vv.z + e21.w * vv.w;
    }
    float a;
    a = 0.5f * (e10.x * i10 + e20.x * i20); ent0 -= a * __logf(a + EPSF);
    a = 0.5f * (e10.y * i10 + e20.y * i20); ent0 -= a * __logf(a + EPSF);
    a = 0.5f * (e10.z * i10 + e20.z * i20); ent0 -= a * __logf(a + EPSF);
    a = 0.5f * (e10.w * i10 + e20.w * i20); ent0 -= a * __logf(a + EPSF);
    a = 0.5f * (e11.x * i11 + e21.x * i21); ent1 -= a * __logf(a + EPSF);
    a = 0.5f * (e11.y * i11 + e21.y * i21); ent1 -= a * __logf(a + EPSF);
    a = 0.5f * (e11.z * i11 + e21.z * i21); ent1 -= a * __logf(a + EPSF);
    a = 0.5f * (e11.w * i11 + e21.w * i21); ent1 -= a * __logf(a + EPSF);
  }
  ent0 = wave_sum(ent0); ent1 = wave_sum(ent1);
#pragma unroll
  for (int d = 0; d < 14; d++) { acc0[d] = wave_sum(acc0[d]); acc1[d] = wave_sum(acc1[d]); }

  if (lane == 0) {
    int row0 = b * 1024 + i0;
    E1o[row0] = 0.5f * i10;  E2o[row0] = 0.5f * i20;
    E1o[row0 + 1] = 0.5f * i11; E2o[row0 + 1] = 0.5f * i21;
#pragma unroll
    for (int d = 0; d < 14; d++) {
      attn_o[row0 * 14 + d] = acc0[d] * (d < 7 ? i10 : i20);
      attn_o[(row0 + 1) * 14 + d] = acc1[d] * (d < 7 ? i11 : i21);
    }
    cert_out[row0] = fmaxf(cert_in[row0], 1.0f / (1.0f + __expf(ent0 - MAXENT)));
    cert_out[row0 + 1] = fmaxf(cert_in[row0 + 1], 1.0f / (1.0f + __expf(ent1 - MAXENT)));
  }
}

// ---------------- kernel 2: output projection ----------------
__global__ __launch_bounds__(256) void proj_kernel(
    const float* __restrict__ attn_o, const float* __restrict__ Wo,
    const float* __restrict__ bo, float* __restrict__ out) {
  int idx = blockIdx.x * 256 + threadIdx.x;     // 917504 = 65536*14
  if (idx >= 917504) return;
  int row = idx / 14, d = idx - row * 14;
  float s = bo[d];
  const float* ar = attn_o + row * 14;
  const float* wr = Wo + d * 14;
#pragma unroll
  for (int k = 0; k < 14; k++) s = fmaf(ar[k], wr[k], s);
  out[idx] = s;
}

// ================= FAST PATH: grouped materialized P0 =================

// precompute P0 for G batches starting at b0; grid = G*32 blocks, 32 rows/block
__global__ __launch_bounds__(512) void p0pre_kernel(
    const float* __restrict__ Qt, const float* __restrict__ Kt,
    const float* __restrict__ E1, const float* __restrict__ E2,
    float* __restrict__ P0, int b0) {
  __shared__ float4 Kl[3584];
  int gb = blockIdx.x >> 5, blk = blockIdx.x & 31;
  int b = b0 + gb;
  int tid = threadIdx.x;
  const float4* Ktb = (const float4*)(Kt + b * 14336);
  for (int idx = tid; idx < 3584; idx += 512) Kl[idx] = Ktb[idx];
  __syncthreads();

  int wave = tid >> 6, lane = tid & 63;
  int i0 = blk * 32 + wave * 4;
  float q[4][14], e1r[4], e2r[4];
#pragma unroll
  for (int rr = 0; rr < 4; rr++) {
#pragma unroll
    for (int d = 0; d < 14; d++) q[rr][d] = Qt[b * 14336 + d * 1024 + i0 + rr];
    e1r[rr] = E1[b * 1024 + i0 + rr];
    e2r[rr] = E2[b * 1024 + i0 + rr];
  }
  float4* P0f4 = (float4*)P0;
#pragma unroll
  for (int t = 0; t < 4; t++) {
    int g = t * 64 + lane;
    float4 kv[14];
#pragma unroll
    for (int d = 0; d < 14; d++) kv[d] = Kl[d * 256 + g];
#pragma unroll
    for (int rr = 0; rr < 4; rr++) {
      float4 s1 = {0,0,0,0}, s2 = {0,0,0,0};
#pragma unroll
      for (int d = 0; d < 7; d++)  fma4(q[rr][d], kv[d], s1);
#pragma unroll
      for (int d = 7; d < 14; d++) fma4(q[rr][d], kv[d], s2);
      float4 pv;
      pv.x = p0e(s1.x, s2.x, e1r[rr], e2r[rr]);
      pv.y = p0e(s1.y, s2.y, e1r[rr], e2r[rr]);
      pv.z = p0e(s1.z, s2.z, e1r[rr], e2r[rr]);
      pv.w = p0e(s1.w, s2.w, e1r[rr], e2r[rr]);
      P0f4[(size_t)(gb * 1024 + i0 + rr) * 256 + g] = pv;
    }
  }
}

// fused Sinkhorn iteration over a group: u = P0.C, R update, v-partials per slice.
// grid = G << logS blocks; rows/block = 1024>>logS (8 waves, rows/wave = 128>>logS)
__global__ __launch_bounds__(512) void sink_fused(
    const float* __restrict__ P0, const float* __restrict__ Cg,
    float* __restrict__ R, float* __restrict__ vpart,
    int b0, int G, int logS) {
  __shared__ float vbuf[1024];
  int tid = threadIdx.x;
  for (int idx = tid; idx < 1024; idx += 512) vbuf[idx] = 0.f;
  __syncthreads();
  int S = 1 << logS;
  int gb = blockIdx.x >> logS, slice = blockIdx.x & (S - 1);
  int b = b0 + gb;
  int wave = tid >> 6, lane = tid & 63;
  const float4* Cb = (const float4*)(Cg + b * 1024);
  float4 c0 = Cb[lane], c1 = Cb[64 + lane], c2 = Cb[128 + lane], c3 = Cb[192 + lane];
  float4 v0 = {0,0,0,0}, v1 = {0,0,0,0}, v2 = {0,0,0,0}, v3 = {0,0,0,0};

  int rpw = 128 >> logS;                        // rows per wave
  int i0 = slice * (1024 >> logS) + wave * rpw;
  const float4* P0f4 = (const float4*)P0;
  for (int r = 0; r < rpw; r++) {
    int i = i0 + r;
    const float4* Prow = P0f4 + (size_t)(gb * 1024 + i) * 256;
    float4 p0 = Prow[lane], p1 = Prow[64 + lane], p2 = Prow[128 + lane], p3 = Prow[192 + lane];
    float u = p0.x * c0.x;
    u = fmaf(p0.y, c0.y, u); u = fmaf(p0.z, c0.z, u); u = fmaf(p0.w, c0.w, u);
    u = fmaf(p1.x, c1.x, u); u = fmaf(p1.y, c1.y, u); u = fmaf(p1.z, c1.z, u); u = fmaf(p1.w, c1.w, u);
    u = fmaf(p2.x, c2.x, u); u = fmaf(p2.y, c2.y, u); u = fmaf(p2.z, c2.z, u); u = fmaf(p2.w, c2.w, u);
    u = fmaf(p3.x, c3.x, u); u = fmaf(p3.y, c3.y, u); u = fmaf(p3.z, c3.z, u); u = fmaf(p3.w, c3.w, u);
    u = wave_sum(u);
    int ri = b * 1024 + i;
    float rv = R[ri];
    rv = fminf(rv / fmaf(rv, u, EPSF), 1e37f);
    if (lane == 0) R[ri] = rv;
    fma4(rv, p0, v0); fma4(rv, p1, v1); fma4(rv, p2, v2); fma4(rv, p3, v3);
  }
  atomicAdd(&vbuf[4 * lane + 0], v0.x); atomicAdd(&vbuf[4 * lane + 1], v0.y);
  atomicAdd(&vbuf[4 * lane + 2], v0.z); atomicAdd(&vbuf[4 * lane + 3], v0.w);
  atomicAdd(&vbuf[256 + 4 * lane + 0], v1.x); atomicAdd(&vbuf[256 + 4 * lane + 1], v1.y);
  atomicAdd(&vbuf[256 + 4 * lane + 2], v1.z); atomicAdd(&vbuf[256 + 4 * lane + 3], v1.w);
  atomicAdd(&vbuf[512 + 4 * lane + 0], v2.x); atomicAdd(&vbuf[512 + 4 * lane + 1], v2.y);
  atomicAdd(&vbuf[512 + 4 * lane + 2], v2.z); atomicAdd(&vbuf[512 + 4 * lane + 3], v2.w);
  atomicAdd(&vbuf[768 + 4 * lane + 0], v3.x); atomicAdd(&vbuf[768 + 4 * lane + 1], v3.y);
  atomicAdd(&vbuf[768 + 4 * lane + 2], v3.z); atomicAdd(&vbuf[768 + 4 * lane + 3], v3.w);
  __syncthreads();
  float* vp = vpart + (size_t)(slice * G + gb) * 1024;
  for (int idx = tid; idx < 1024; idx += 512) vp[idx] = vbuf[idx];
}

// C update: v = sum of S slice partials, then C = C/(C*v+eps)
__global__ __launch_bounds__(256) void cupdate_kernel(
    float* __restrict__ C, const float* __restrict__ vpart, int b0, int G, int S) {
  int idx = blockIdx.x * 256 + threadIdx.x;     // < G*1024
  int gb = idx >> 10, j = idx & 1023;
  float v = 0.f;
  for (int s = 0; s < S; s++) v += vpart[(size_t)(s * G + gb) * 1024 + j];
  int o = (b0 + gb) * 1024 + j;
  float cv = C[o];
  C[o] = fminf(cv / fmaf(cv, v, EPSF), 1e37f);
}

// argmax over stored P0 * C + permutation gather; grid = G*128
__global__ __launch_bounds__(512) void argmaxP_kernel(
    const float* __restrict__ P0, const float* __restrict__ Cg,
    const int* __restrict__ perm, float* __restrict__ perm_out, int b0) {
  int gb = blockIdx.x >> 7, rg = blockIdx.x & 127;
  int b = b0 + gb;
  int tid = threadIdx.x;
  int wave = tid >> 6, lane = tid & 63;
  int i = rg * 8 + wave;
  const float4* Cb = (const float4*)(Cg + b * 1024);
  const float4* Prow = (const float4*)P0 + (size_t)(gb * 1024 + i) * 256;

  float best = -1.0f;
  int bj = 0;
#pragma unroll
  for (int t = 0; t < 4; t++) {
    int g = t * 64 + lane;
    float4 pv = Prow[g], cv = Cb[g];
    float val;
    val = pv.x * cv.x; if (val > best) { best = val; bj = 4 * g + 0; }
    val = pv.y * cv.y; if (val > best) { best = val; bj = 4 * g + 1; }
    val = pv.z * cv.z; if (val > best) { best = val; bj = 4 * g + 2; }
    val = pv.w * cv.w; if (val > best) { best = val; bj = 4 * g + 3; }
  }
#pragma unroll
  for (int off = 32; off > 0; off >>= 1) {
    float ob = __shfl_xor(best, off);
    int oj = __shfl_xor(bj, off);
    if (ob > best || (ob == best && oj < bj)) { best = ob; bj = oj; }
  }
  if (lane == 0) perm_out[b * 1024 + i] = (float)perm[b * 1024 + bj];
}

// ================= FALLBACK PATH (round-3, recompute) =================

__global__ __launch_bounds__(512) void sinkA_kernel(
    const float* __restrict__ Qt, const float* __restrict__ Kt,
    const float* __restrict__ E1, const float* __restrict__ E2,
    const float* __restrict__ C, float* __restrict__ R) {
  __shared__ float4 Kl[3584];
  int b = blockIdx.x >> 5, blk = blockIdx.x & 31;
  int tid = threadIdx.x;
  const float4* Ktb = (const float4*)(Kt + b * 14336);
  for (int idx = tid; idx < 3584; idx += 512) Kl[idx] = Ktb[idx];
  __syncthreads();
  int wave = tid >> 6, lane = tid & 63;
  int i0 = blk * 32 + wave * 4;
  float q[4][14], e1r[4], e2r[4], u[4];
#pragma unroll
  for (int rr = 0; rr < 4; rr++) {
#pragma unroll
    for (int d = 0; d < 14; d++) q[rr][d] = Qt[b * 14336 + d * 1024 + i0 + rr];
    e1r[rr] = E1[b * 1024 + i0 + rr];
    e2r[rr] = E2[b * 1024 + i0 + rr];
    u[rr] = 0.f;
  }
  const float4* Cb = (const float4*)(C + b * 1024);
#pragma unroll
  for (int t = 0; t < 4; t++) {
    int g = t * 64 + lane;
    float4 kv[14];
#pragma unroll
    for (int d = 0; d < 14; d++) kv[d] = Kl[d * 256 + g];
    float4 cv = Cb[g];
#pragma unroll
    for (int rr = 0; rr < 4; rr++) {
      float4 s1 = {0,0,0,0}, s2 = {0,0,0,0};
#pragma unroll
      for (int d = 0; d < 7; d++)  fma4(q[rr][d], kv[d], s1);
#pragma unroll
      for (int d = 7; d < 14; d++) fma4(q[rr][d], kv[d], s2);
      u[rr] += p0e(s1.x, s2.x, e1r[rr], e2r[rr]) * cv.x;
      u[rr] += p0e(s1.y, s2.y, e1r[rr], e2r[rr]) * cv.y;
      u[rr] += p0e(s1.z, s2.z, e1r[rr], e2r[rr]) * cv.z;
      u[rr] += p0e(s1.w, s2.w, e1r[rr], e2r[rr]) * cv.w;
    }
  }
#pragma unroll
  for (int rr = 0; rr < 4; rr++) u[rr] = wave_sum(u[rr]);
  if (lane == 0) {
#pragma unroll
    for (int rr = 0; rr < 4; rr++) {
      int o = b * 1024 + i0 + rr;
      float rv = R[o];
      R[o] = fminf(rv / fmaf(rv, u[rr], EPSF), 1e37f);
    }
  }
}

__global__ __launch_bounds__(512) void sinkB_kernel(
    const float* __restrict__ Qt, const float* __restrict__ Kt,
    const float* __restrict__ E1, const float* __restrict__ E2,
    const float* __restrict__ R, float* __restrict__ C) {
  __shared__ float4 Ql[3584];
  int b = blockIdx.x >> 5, blk = blockIdx.x & 31;
  int tid = threadIdx.x;
  const float4* Qtb = (const float4*)(Qt + b * 14336);
  for (int idx = tid; idx < 3584; idx += 512) Ql[idx] = Qtb[idx];
  __syncthreads();
  int wave = tid >> 6, lane = tid & 63;
  int j0 = blk * 32 + wave * 4;
  float kk[4][14], v[4];
#pragma unroll
  for (int rr = 0; rr < 4; rr++) {
#pragma unroll
    for (int d = 0; d < 14; d++) kk[rr][d] = Kt[b * 14336 + d * 1024 + j0 + rr];
    v[rr] = 0.f;
  }
  const float4* E1b = (const float4*)(E1 + b * 1024);
  const float4* E2b = (const float4*)(E2 + b * 1024);
  const float4* Rb  = (const float4*)(R + b * 1024);
#pragma unroll
  for (int t = 0; t < 4; t++) {
    int g = t * 64 + lane;
    float4 qv[14];
#pragma unroll
    for (int d = 0; d < 14; d++) qv[d] = Ql[d * 256 + g];
    float4 e1v = E1b[g], e2v = E2b[g], rv = Rb[g];
#pragma unroll
    for (int rr = 0; rr < 4; rr++) {
      float4 s1 = {0,0,0,0}, s2 = {0,0,0,0};
#pragma unroll
      for (int d = 0; d < 7; d++)  fma4(kk[rr][d], qv[d], s1);
#pragma unroll
      for (int d = 7; d < 14; d++) fma4(kk[rr][d], qv[d], s2);
      v[rr] += p0e(s1.x, s2.x, e1v.x, e2v.x) * rv.x;
      v[rr] += p0e(s1.y, s2.y, e1v.y, e2v.y) * rv.y;
      v[rr] += p0e(s1.z, s2.z, e1v.z, e2v.z) * rv.z;
      v[rr] += p0e(s1.w, s2.w, e1v.w, e2v.w) * rv.w;
    }
  }
#pragma unroll
  for (int rr = 0; rr < 4; rr++) v[rr] = wave_sum(v[rr]);
  if (lane == 0) {
#pragma unroll
    for (int rr = 0; rr < 4; rr++) {
      int o = b * 1024 + j0 + rr;
      float cv = C[o];
      C[o] = fminf(cv / fmaf(cv, v[rr], EPSF), 1e37f);
    }
  }
}

__global__ __launch_bounds__(512) void argmax_kernel(
    const float* __restrict__ Qt, const float* __restrict__ Kt,
    const float* __restrict__ E1, const float* __restrict__ E2,
    const float* __restrict__ C, const int* __restrict__ perm,
    float* __restrict__ perm_out) {
  __shared__ float4 Kl[3584];
  int b = blockIdx.x >> 7, rg = blockIdx.x & 127;
  int tid = threadIdx.x;
  const float4* Ktb = (const float4*)(Kt + b * 14336);
  for (int idx = tid; idx < 3584; idx += 512) Kl[idx] = Ktb[idx];
  __syncthreads();
  int wave = tid >> 6, lane = tid & 63;
  int i = rg * 8 + wave;
  int row = b * 1024 + i;
  float q[14];
#pragma unroll
  for (int d = 0; d < 14; d++) q[d] = Qt[b * 14336 + d * 1024 + i];
  float e1r = E1[row], e2r = E2[row];
  const float4* Cb = (const float4*)(C + b * 1024);
  float best = -1.0f;
  int bj = 0;
#pragma unroll
  for (int t = 0; t < 4; t++) {
    int g = t * 64 + lane;
    float4 kv[14];
#pragma unroll
    for (int d = 0; d < 14; d++) kv[d] = Kl[d * 256 + g];
    float4 cv = Cb[g];
    float4 s1 = {0,0,0,0}, s2 = {0,0,0,0};
#pragma unroll
    for (int d = 0; d < 7; d++)  fma4(q[d], kv[d], s1);
#pragma unroll
    for (int d = 7; d < 14; d++) fma4(q[d], kv[d], s2);
    float val;
    val = p0e(s1.x, s2.x, e1r, e2r) * cv.x; if (val > best) { best = val; bj = 4 * g + 0; }
    val = p0e(s1.y, s2.y, e1r, e2r) * cv.y; if (val > best) { best = val; bj = 4 * g + 1; }
    val = p0e(s1.z, s2.z, e1r, e2r) * cv.z; if (val > best) { best = val; bj = 4 * g + 2; }
    val = p0e(s1.w, s2.w, e1r, e2r) * cv.w; if (val > best) { best = val; bj = 4 * g + 3; }
  }
#pragma unroll
  for (int off = 32; off > 0; off >>= 1) {
    float ob = __shfl_xor(best, off);
    int oj = __shfl_xor(bj, off);
    if (ob > best || (ob == best && oj < bj)) { best = ob; bj = oj; }
  }
  if (lane == 0) perm_out[row] = (float)perm[b * 1024 + bj];
}

// ---------------- launch ----------------
extern "C" void kernel_launch(void* const* d_in, const int* in_sizes, int n_in,
                              void* d_out, int out_size, void* d_ws, size_t ws_size,
                              hipStream_t stream) {
  const float* x    = (const float*)d_in[0];
  const float* cert = (const float*)d_in[1];
  const int*   perm = (const int*)d_in[2];
  const float* Wq = (const float*)d_in[3];
  const float* bq = (const float*)d_in[4];
  const float* Wk = (const float*)d_in[5];
  const float* bk = (const float*)d_in[6];
  const float* Wv = (const float*)d_in[7];
  const float* bv = (const float*)d_in[8];
  const float* Wo = (const float*)d_in[9];
  const float* bo = (const float*)d_in[10];

  float* out      = (float*)d_out;            // 917504
  float* cert_out = out + 917504;             // 65536
  float* perm_out = out + 983040;             // 65536

  float* ws = (float*)d_ws;
  float* Qt = ws;                    // 917504
  float* Kt = Qt + 917504;           // 917504
  float* Vt = Kt + 917504;           // 917504
  float* E1 = Vt + 917504;           // 65536
  float* E2 = E1 + 65536;            // 65536
  float* R  = E2 + 65536;            // 65536
  float* C  = R + 65536;             // 65536
  float* attn_o = C + 65536;         // 917504  (fallback footprint ends: 3,932,160 floats)
  float* vpart  = attn_o + 917504;   // 2,097,152 (fast path only)
  float* P0     = vpart + 2097152;   // G * 1,048,576 (fast path only)

  // choose batch-group size G by available workspace
  size_t base_f = 3932160u + 2097152u;
  size_t avail_f = (ws_size / 4 > base_f) ? (ws_size / 4 - base_f) : 0;
  int G = (int)(avail_f >> 20);                 // 1,048,576 floats per batch
  if (G >= 64) G = 64; else if (G >= 32) G = 32; else if (G >= 16) G = 16; else G = 0;

  qkv_kernel<<<256, 256, 0, stream>>>(x, Wq, bq, Wk, bk, Wv, bv, Qt, Kt, Vt, R, C);
  attn_kernel<<<4096, 512, 0, stream>>>(Qt, Kt, Vt, cert, E1, E2, attn_o, cert_out);
  proj_kernel<<<3584, 256, 0, stream>>>(attn_o, Wo, bo, out);

  if (G >= 16) {
    int logS = (G >= 32) ? 4 : 5;               // 16 slices for big G, 32 for G=16
    int S = 1 << logS;
    for (int b0 = 0; b0 < 64; b0 += G) {
      p0pre_kernel<<<G * 32, 512, 0, stream>>>(Qt, Kt, E1, E2, P0, b0);
      for (int it = 0; it < 20; it++) {
        sink_fused<<<G << logS, 512, 0, stream>>>(P0, C, R, vpart, b0, G, logS);
        cupdate_kernel<<<G * 4, 256, 0, stream>>>(C, vpart, b0, G, S);
      }
      argmaxP_kernel<<<G * 128, 512, 0, stream>>>(P0, C, perm, perm_out, b0);
    }
  } else {
    for (int it = 0; it < 20; it++) {
      sinkA_kernel<<<2048, 512, 0, stream>>>(Qt, Kt, E1, E2, C, R);
      sinkB_kernel<<<2048, 512, 0, stream>>>(Qt, Kt, E1, E2, R, C);
    }
    argmax_kernel<<<8192, 512, 0, stream>>>(Qt, Kt, E1, E2, C, perm, perm_out);
  }
}